// Round 7
// baseline (54.210 us; speedup 1.0000x reference)
//
#include <hip/hip_runtime.h>
#include <hip/hip_fp16.h>

#define KN    4096
#define LTOT  6
#define BATCH 8192
#define ROWS  4
#define NT    512
#define NITER (KN / NT)          // 8
#define NBLK  (BATCH / ROWS)     // 2048
#define NWAVE (NT / 64)          // 8

#if __has_builtin(__builtin_amdgcn_cvt_pk_u8_f32)
#define CVT_PK_U8(o, r, enc) __builtin_amdgcn_cvt_pk_u8_f32((o), (r), (enc))
#else
#define CVT_PK_U8(o, r, enc) ((enc) | ((unsigned)(int)(o) << (8 * (r))))
#endif

// Operand arrays (split so the hot loop does zero coefficient unpacking):
//   pidx[l*KN+k]  = (ia*4) | ((ib*4) << 16)            -- pre-scaled LDS byte offsets
//   pcoef[l*KN+k] = {255*c1 + 0.5, ca, cb, cab/255}    -- raw fp32
__global__ __launch_bounds__(256) void pack_kernel(const float* __restrict__ w0,
                                                   const float* __restrict__ ws,
                                                   const int* __restrict__ idx0,
                                                   const int* __restrict__ idxs,
                                                   unsigned* __restrict__ pidx,
                                                   float4* __restrict__ pcoef) {
    const float TAB[16][4] = {
        {0.f, 0.f, 0.f, 0.f}, {0.f, 0.f, 0.f, 1.f}, {0.f, 1.f, 0.f,-1.f}, {0.f, 1.f, 0.f, 0.f},
        {0.f, 0.f, 1.f,-1.f}, {0.f, 0.f, 1.f, 0.f}, {0.f, 1.f, 1.f,-2.f}, {0.f, 1.f, 1.f,-1.f},
        {1.f,-1.f,-1.f, 1.f}, {1.f,-1.f,-1.f, 2.f}, {1.f, 0.f,-1.f, 0.f}, {1.f, 0.f,-1.f, 1.f},
        {1.f,-1.f, 0.f, 0.f}, {1.f,-1.f, 0.f, 1.f}, {1.f, 0.f, 0.f,-1.f}, {1.f, 0.f, 0.f, 0.f}
    };
    int gid = blockIdx.x * 256 + threadIdx.x;
    if (gid >= LTOT * KN) return;
    int l = gid >> 12;
    int k = gid & (KN - 1);
    const float* w = (l == 0) ? (w0 + k * 16) : (ws + ((size_t)((l - 1) * KN + k) << 4));
    float wv[16];
    float m = -1e30f;
#pragma unroll
    for (int j = 0; j < 16; ++j) { wv[j] = w[j]; m = fmaxf(m, wv[j]); }
    float s = 0.f;
#pragma unroll
    for (int j = 0; j < 16; ++j) { wv[j] = __expf(wv[j] - m); s += wv[j]; }
    float inv = 1.0f / s;
    float c0 = 0.f, c1 = 0.f, c2 = 0.f, c3 = 0.f;
#pragma unroll
    for (int j = 0; j < 16; ++j) {
        c0 += wv[j] * TAB[j][0];
        c1 += wv[j] * TAB[j][1];
        c2 += wv[j] * TAB[j][2];
        c3 += wv[j] * TAB[j][3];
    }
    c0 *= inv; c1 *= inv; c2 *= inv; c3 *= inv;

    pcoef[gid] = make_float4(255.0f * c0 + 0.5f, c1, c2, c3 * (1.0f / 255.0f));

    int ia, ib;
    if (l == 0) { ia = idx0[k];                            ib = idx0[KN + k]; }
    else        { ia = idxs[(size_t)(l - 1) * 2 * KN + k]; ib = idxs[(size_t)(l - 1) * 2 * KN + KN + k]; }
    pidx[gid] = ((unsigned)ia * 4u) | (((unsigned)ib * 4u) << 16);
}

// One block = 4 batch rows packed as 4x u8 per neuron (one u32) in LDS.
// hbuf = 2 x 16 KB -> 4 blocks/CU, 32 waves/CU.
__global__ __launch_bounds__(NT, 8) void fused_kernel(const float* __restrict__ x,
                                                      const unsigned* __restrict__ pidx,
                                                      const float4* __restrict__ pcoef,
                                                      float* __restrict__ out) {
    __shared__ unsigned hbuf[2][KN];     // 32 KB
    __shared__ float red[NWAVE][8];

    const int t  = threadIdx.x;
    const int b0 = blockIdx.x * ROWS;

    // Features as 0/255 floats per row.
    float f0[ROWS], f1[ROWS];
#pragma unroll
    for (int r = 0; r < ROWS; ++r) {
        f0[r] = x[(size_t)(b0 + r) * 2 + 0] > 0.f ? 255.f : 0.f;
        f1[r] = x[(size_t)(b0 + r) * 2 + 1] > 0.f ? 255.f : 0.f;
    }

    // ---- Layer 0: 2 -> K, writes hbuf[0] ----
#pragma unroll
    for (int i = 0; i < NITER; ++i) {
        int k = t + i * NT;
        unsigned px = pidx[k];
        float4   c  = pcoef[k];
        unsigned enc = 0;
#pragma unroll
        for (int r = 0; r < ROWS; ++r) {
            float A = (px & 0xffffu) ? f1[r] : f0[r];
            float B = (px >> 16)     ? f1[r] : f0[r];
            float o = fmaf(fmaf(c.w, B, c.y), A, fmaf(c.z, B, c.x));
            enc = CVT_PK_U8(o, r, enc);
        }
        hbuf[0][k] = enc;
    }
    __syncthreads();

    // ---- Layers 1..4: K -> K, ping-pong ----
#pragma unroll
    for (int l = 1; l <= 4; ++l) {
        const unsigned* __restrict__ pi = pidx  + (size_t)l * KN;
        const float4*   __restrict__ pc = pcoef + (size_t)l * KN;
        const char* hs = (const char*)&hbuf[(l + 1) & 1][0];
        unsigned*   hd = &hbuf[l & 1][0];
#pragma unroll
        for (int i = 0; i < NITER; ++i) {
            int k = t + i * NT;
            unsigned px = pi[k];
            float4   c  = pc[k];
            unsigned av = *(const unsigned*)(hs + (px & 0xffffu));
            unsigned bv = *(const unsigned*)(hs + (px >> 16));
            unsigned enc = 0;
#pragma unroll
            for (int r = 0; r < ROWS; ++r) {
                float A = (float)((av >> (8 * r)) & 0xffu);
                float B = (float)((bv >> (8 * r)) & 0xffu);
                float o = fmaf(fmaf(c.w, B, c.y), A, fmaf(c.z, B, c.x));
                enc = CVT_PK_U8(o, r, enc);
            }
            hd[k] = enc;
        }
        __syncthreads();
    }

    // ---- Layer 5 fused with GroupSum (reads hbuf[0], no quantize/write) ----
    float acc[8];    // [class*4 + row], values are 255*f + 0.5
#pragma unroll
    for (int j = 0; j < 8; ++j) acc[j] = 0.f;
    {
        const unsigned* __restrict__ pi = pidx  + (size_t)5 * KN;
        const float4*   __restrict__ pc = pcoef + (size_t)5 * KN;
        const char* hs = (const char*)&hbuf[0][0];
#pragma unroll
        for (int i = 0; i < NITER; ++i) {
            int k = t + i * NT;
            unsigned px = pi[k];
            float4   c  = pc[k];
            unsigned av = *(const unsigned*)(hs + (px & 0xffffu));
            unsigned bv = *(const unsigned*)(hs + (px >> 16));
            const int cbase = (i >= 4) ? 4 : 0;   // class from k = t + i*512
#pragma unroll
            for (int r = 0; r < ROWS; ++r) {
                float A = (float)((av >> (8 * r)) & 0xffu);
                float B = (float)((bv >> (8 * r)) & 0xffu);
                acc[cbase + r] += fmaf(fmaf(c.w, B, c.y), A, fmaf(c.z, B, c.x));
            }
        }
    }
#pragma unroll
    for (int j = 0; j < 8; ++j)
#pragma unroll
        for (int off = 32; off > 0; off >>= 1)
            acc[j] += __shfl_down(acc[j], off);
    int wave = t >> 6, lane = t & 63;
    if (lane == 0) {
#pragma unroll
        for (int j = 0; j < 8; ++j) red[wave][j] = acc[j];
    }
    __syncthreads();
    if (t < 8) {
        float s = 0.f;
#pragma unroll
        for (int w = 0; w < NWAVE; ++w) s += red[w][t];
        // Each class-sum accumulated 2048 terms of (255*f + 0.5).
        s = (s - 1024.0f) * (1.0f / 255.0f);
        int cls = t >> 2, row = t & 3;
        out[(size_t)(b0 + row) * 2 + cls] = s;
    }
}

extern "C" void kernel_launch(void* const* d_in, const int* in_sizes, int n_in,
                              void* d_out, int out_size, void* d_ws, size_t ws_size,
                              hipStream_t stream) {
    const float* x    = (const float*)d_in[0];
    const float* w0   = (const float*)d_in[1];
    const float* ws   = (const float*)d_in[2];
    const int*   idx0 = (const int*)d_in[3];
    const int*   idxs = (const int*)d_in[4];
    float*       out  = (float*)d_out;

    float4*   pcoef = (float4*)d_ws;                   // LTOT*KN*16 B = 384 KB
    unsigned* pidx  = (unsigned*)(pcoef + LTOT * KN);  // LTOT*KN*4 B  =  96 KB

    pack_kernel<<<(LTOT * KN + 255) / 256, 256, 0, stream>>>(w0, ws, idx0, idxs, pidx, pcoef);
    fused_kernel<<<NBLK, NT, 0, stream>>>(x, pidx, pcoef, out);
}